// Round 10
// baseline (135.114 us; speedup 1.0000x reference)
//
#include <hip/hip_runtime.h>
#include <math.h>

// ---------------------------------------------------------------------------
// WCSA round 10 = round 9 (passing) + ONE change: XCD-aware block swizzle on
// the spatial kernel (T1). Theory: r6-r9 are L3-BW-bound (~800 MB beyond-L2
// reads at ~10 TB/s = the invariant 78 us) because round-robin dispatch
// scatters each head's blocks over all 8 XCDs (per-XCD working set 9 MB >
// 4 MB L2). Swizzle pins 2 heads per XCD (640 KB hot set -> L2-resident).
// Math bit-identical to r9. Projections/channel branch unchanged (verified).
// ---------------------------------------------------------------------------

constexpr int Bb = 4, Nn = 2048, Hh = 4;
constexpr int PROJ_EL = Nn * 256;          // elements per batch, 256-col proj
constexpr int HEAD_EL = Nn * 64;           // elements per (b,h) head, d=64

typedef __attribute__((ext_vector_type(8))) short short8_t;   // 8 bf16
typedef __attribute__((ext_vector_type(4))) float f32x4;

__device__ __forceinline__ ushort f2bf(float x) {
    union { float f; unsigned u; } v; v.f = x;
    unsigned r = v.u + 0x7fffu + ((v.u >> 16) & 1u);   // RNE
    return (ushort)(r >> 16);
}
__device__ __forceinline__ float bf2f(ushort x) {
    union { unsigned u; float f; } v; v.u = ((unsigned)x) << 16;
    return v.f;
}

// ---------------- workspace layout (float granularity) ---------------------
constexpr size_t OFF_SB    = 0;                                   // s bf16
constexpr size_t OFF_SHB   = OFF_SB   + 1024 * 1024;              // sh bf16
constexpr size_t OFF_HB    = OFF_SHB  + 1024 * 1024;              // h bf16
constexpr size_t OFF_WQC   = OFF_HB   + 256 * 1024;               // Wq_c bf16
constexpr size_t OFF_WCAT  = OFF_WQC  + 32 * 1024;                // 4x64K el
constexpr size_t OFF_PQC   = OFF_WCAT + 128 * 1024;               // bf16 (8192,256)
constexpr size_t OFF_PQS   = OFF_PQC  + 1024 * 1024;
constexpr size_t OFF_PKC   = OFF_PQS  + 1024 * 1024;
constexpr size_t OFF_PVC   = OFF_PKC  + 1024 * 1024;
constexpr size_t OFF_PKS   = OFF_PVC  + 1024 * 1024;
constexpr size_t OFF_PVST  = OFF_PKS  + 1024 * 1024;              // bf16 (B,H,16,2048)
constexpr size_t OFF_PART  = OFF_PVST + 256 * 1024;               // f32 16*8*4096
constexpr size_t OFF_SCA   = OFF_PART + 512 * 1024;               // bf16 16*4096
constexpr size_t OFF_WVS   = OFF_SCA  + 32 * 1024;                // Wv_s bf16 (64,64)

// ---------------------------------------------------------------------------
// Convert all needed f32 arrays to bf16 in one pass. 8 elements per thread.
// ---------------------------------------------------------------------------
constexpr unsigned SEG0 = 2097152;              // s
constexpr unsigned SEG1 = SEG0 + 2097152;       // sh
constexpr unsigned SEG2 = SEG1 + 524288;        // h
constexpr unsigned SEG3 = SEG2 + 65536;         // Wq_c
constexpr unsigned SEG4 = SEG3 + 65536;         // Wq_s  -> Wcat+0
constexpr unsigned SEG5 = SEG4 + 65536;         // Wk_c  -> Wcat+65536
constexpr unsigned SEG6 = SEG5 + 65536;         // Wv_c  -> Wcat+131072
constexpr unsigned SEG7 = SEG6 + 65536;         // Wk_s  -> Wcat+196608
constexpr unsigned SEG8 = SEG7 + 4096;          // Wv_s

__global__ __launch_bounds__(256) void convert_all(
    const float* __restrict__ s, const float* __restrict__ sh,
    const float* __restrict__ h, const float* __restrict__ wqc,
    const float* __restrict__ wqs, const float* __restrict__ wkc,
    const float* __restrict__ wvc, const float* __restrict__ wks,
    const float* __restrict__ wvs,
    ushort* __restrict__ sb, ushort* __restrict__ shb, ushort* __restrict__ hb,
    ushort* __restrict__ wqcb, ushort* __restrict__ wcatb, ushort* __restrict__ wvsb)
{
    unsigned e = (blockIdx.x * 256u + threadIdx.x) * 8u;
    if (e >= SEG8) return;
    const float* src; ushort* dst; unsigned off;
    if      (e < SEG0) { src = s;   dst = sb;             off = e; }
    else if (e < SEG1) { src = sh;  dst = shb;            off = e - SEG0; }
    else if (e < SEG2) { src = h;   dst = hb;             off = e - SEG1; }
    else if (e < SEG3) { src = wqc; dst = wqcb;           off = e - SEG2; }
    else if (e < SEG4) { src = wqs; dst = wcatb;          off = e - SEG3; }
    else if (e < SEG5) { src = wkc; dst = wcatb + 65536;  off = e - SEG4; }
    else if (e < SEG6) { src = wvc; dst = wcatb + 131072; off = e - SEG5; }
    else if (e < SEG7) { src = wks; dst = wcatb + 196608; off = e - SEG6; }
    else               { src = wvs; dst = wvsb;           off = e - SEG7; }
    float4 f0 = *(const float4*)&src[off];
    float4 f1 = *(const float4*)&src[off + 4];
    short8_t o;
    o[0] = f2bf(f0.x); o[1] = f2bf(f0.y); o[2] = f2bf(f0.z); o[3] = f2bf(f0.w);
    o[4] = f2bf(f1.x); o[5] = f2bf(f1.y); o[6] = f2bf(f1.z); o[7] = f2bf(f1.w);
    *(short8_t*)&dst[off] = o;
}

// ---------------------------------------------------------------------------
// bf16 MFMA GEMM: C = X(M,K) @ W(Ntot,K)^T, bf16 out, routed to one of four
// 256-col destination buffers by global column segment. 128x128 tile, BK=64.
// (unchanged from round 3, verified)
// ---------------------------------------------------------------------------
__global__ __launch_bounds__(256) void mfma_gemm(
    const ushort* __restrict__ X, const ushort* __restrict__ W,
    ushort* __restrict__ d0, ushort* __restrict__ d1,
    ushort* __restrict__ d2, ushort* __restrict__ d3, int K)
{
    __shared__ ushort Xs[128][72];
    __shared__ ushort Ws[128][72];
    const int t = threadIdx.x;
    const int w = t >> 6, l = t & 63, c = l & 15, g = l >> 4;
    const int wr = w >> 1, wc = w & 1;
    const int m0 = blockIdx.y * 128, n0 = blockIdx.x * 128;

    f32x4 acc[4][4] = {};

    const int srow = t >> 2, scs = (t & 3) * 16;
    for (int k0 = 0; k0 < K; k0 += 64) {
        __syncthreads();
        #pragma unroll
        for (int p = 0; p < 2; ++p) {
            const ushort* xs = &X[(size_t)(m0 + p * 64 + srow) * K + k0 + scs];
            *(short8_t*)&Xs[p * 64 + srow][scs]     = *(const short8_t*)xs;
            *(short8_t*)&Xs[p * 64 + srow][scs + 8] = *(const short8_t*)(xs + 8);
            const ushort* wsp = &W[(size_t)(n0 + p * 64 + srow) * K + k0 + scs];
            *(short8_t*)&Ws[p * 64 + srow][scs]     = *(const short8_t*)wsp;
            *(short8_t*)&Ws[p * 64 + srow][scs + 8] = *(const short8_t*)(wsp + 8);
        }
        __syncthreads();
        #pragma unroll
        for (int ks = 0; ks < 2; ++ks) {
            short8_t af[4], bf[4];
            #pragma unroll
            for (int rt = 0; rt < 4; ++rt)
                af[rt] = *(const short8_t*)&Xs[wr * 64 + rt * 16 + c][ks * 32 + 8 * g];
            #pragma unroll
            for (int ct = 0; ct < 4; ++ct)
                bf[ct] = *(const short8_t*)&Ws[wc * 64 + ct * 16 + c][ks * 32 + 8 * g];
            #pragma unroll
            for (int rt = 0; rt < 4; ++rt)
                #pragma unroll
                for (int ct = 0; ct < 4; ++ct)
                    acc[rt][ct] = __builtin_amdgcn_mfma_f32_16x16x32_bf16(
                        af[rt], bf[ct], acc[rt][ct], 0, 0, 0);
        }
    }

    const int seg = n0 >> 8;
    ushort* dst = seg == 0 ? d0 : seg == 1 ? d1 : seg == 2 ? d2 : d3;
    const int colbase = (n0 & 255) + wc * 64;
    #pragma unroll
    for (int rt = 0; rt < 4; ++rt)
        #pragma unroll
        for (int ct = 0; ct < 4; ++ct)
            #pragma unroll
            for (int r = 0; r < 4; ++r) {
                int mrow = m0 + wr * 64 + rt * 16 + 4 * g + r;
                int col = colbase + ct * 16 + c;
                dst[(size_t)mrow * 256 + col] = f2bf(acc[rt][ct][r]);
            }
}

// ---------------------------------------------------------------------------
// v_s^T producer with raw-reshape-aware scatter (verified round 6).
// ---------------------------------------------------------------------------
__global__ __launch_bounds__(256) void mfma_gemm_vs(
    const ushort* __restrict__ Wvs, const ushort* __restrict__ Hb,
    ushort* __restrict__ Cvt)
{
    const int t = threadIdx.x;
    const int w = t >> 6, l = t & 63, c = l & 15, g = l >> 4;
    const int n0 = blockIdx.x * 256 + w * 64;

    f32x4 acc[4][4] = {};
    #pragma unroll
    for (int ks = 0; ks < 2; ++ks) {
        short8_t af[4], bfr[4];
        #pragma unroll
        for (int rt = 0; rt < 4; ++rt)
            af[rt] = *(const short8_t*)&Wvs[(size_t)(rt * 16 + c) * 64 + ks * 32 + 8 * g];
        #pragma unroll
        for (int ct = 0; ct < 4; ++ct)
            bfr[ct] = *(const short8_t*)&Hb[(size_t)(n0 + ct * 16 + c) * 64 + ks * 32 + 8 * g];
        #pragma unroll
        for (int rt = 0; rt < 4; ++rt)
            #pragma unroll
            for (int ct = 0; ct < 4; ++ct)
                acc[rt][ct] = __builtin_amdgcn_mfma_f32_16x16x32_bf16(
                    af[rt], bfr[ct], acc[rt][ct], 0, 0, 0);
    }
    #pragma unroll
    for (int rt = 0; rt < 4; ++rt)
        #pragma unroll
        for (int ct = 0; ct < 4; ++ct)
            #pragma unroll
            for (int r = 0; r < 4; ++r) {
                int cc = rt * 16 + 4 * g + r;       // output channel 0..63
                int m  = n0 + ct * 16 + c;          // global row 0..8191
                int b  = m >> 11, n = m & 2047;
                int L  = n * 64 + cc;               // within-batch flat index
                int hh = L >> 15;
                int k  = (L & 32767) >> 4;
                int d  = L & 15;
                Cvt[(size_t)((b * 4 + hh) * 16 + d) * 2048 + k] = f2bf(acc[rt][ct][r]);
            }
}

// ---------------------------------------------------------------------------
// Channel stage 1 (f32 compute, bf16 input) — unchanged from round 3.
// ---------------------------------------------------------------------------
__global__ __launch_bounds__(256) void chan_qk_partial(const ushort* __restrict__ Pqc,
                                                       const ushort* __restrict__ Pkc,
                                                       float* __restrict__ part)
{
    const int ch = blockIdx.x, hh = blockIdx.y, b = blockIdx.z;
    const ushort* Q = Pqc + (size_t)b * PROJ_EL + (size_t)hh * HEAD_EL;
    const ushort* Kk = Pkc + (size_t)b * PROJ_EL + (size_t)hh * HEAD_EL;
    __shared__ float Qs[64][68], Ks[64][68];
    const int t = threadIdx.x, ty = t >> 4, tx = t & 15;

    float acc[4][4] = {};
    for (int sub = 0; sub < 4; ++sub) {
        const int r0 = ch * 256 + sub * 64;
        __syncthreads();
        #pragma unroll
        for (int q = t; q < 512; q += 256) {
            int row = q >> 3, c8 = (q & 7) * 8;
            short8_t qv = *(const short8_t*)&Q[(size_t)(r0 + row) * 64 + c8];
            short8_t kv = *(const short8_t*)&Kk[(size_t)(r0 + row) * 64 + c8];
            #pragma unroll
            for (int j = 0; j < 8; ++j) {
                Qs[row][c8 + j] = bf2f((ushort)qv[j]);
                Ks[row][c8 + j] = bf2f((ushort)kv[j]);
            }
        }
        __syncthreads();
        #pragma unroll 8
        for (int nn = 0; nn < 64; ++nn) {
            float4 q4 = *(const float4*)&Qs[nn][ty * 4];
            float4 k4 = *(const float4*)&Ks[nn][tx * 4];
            float qa[4] = {q4.x, q4.y, q4.z, q4.w};
            float ka[4] = {k4.x, k4.y, k4.z, k4.w};
            #pragma unroll
            for (int ii = 0; ii < 4; ++ii)
                #pragma unroll
                for (int jj = 0; jj < 4; ++jj)
                    acc[ii][jj] += qa[ii] * ka[jj];
        }
    }
    float* P = part + (((size_t)(b * 4 + hh) * 8 + ch) << 12);
    #pragma unroll
    for (int ii = 0; ii < 4; ++ii)
        *(float4*)&P[(ty * 4 + ii) * 64 + tx * 4] =
            make_float4(acc[ii][0], acc[ii][1], acc[ii][2], acc[ii][3]);
}

// ---------------------------------------------------------------------------
// Channel stage 2 — unchanged from round 3.
// ---------------------------------------------------------------------------
__global__ __launch_bounds__(64) void chan_softmax(const float* __restrict__ part,
                                                   const float* __restrict__ temp,
                                                   ushort* __restrict__ Sca)
{
    const int bh = blockIdx.x;
    const int hsel = bh & 3;
    const int i = threadIdx.x;
    __shared__ float Ss[64][65];
    const float sT = 0.125f * temp[hsel];

    float m = -1e30f;
    for (int j = 0; j < 64; ++j) {
        float v = 0.f;
        #pragma unroll
        for (int cc = 0; cc < 8; ++cc)
            v += part[((size_t)bh * 8 + cc) * 4096 + i * 64 + j];
        v *= sT;
        Ss[i][j] = v;
        m = fmaxf(m, v);
    }
    float sum = 0.f;
    for (int j = 0; j < 64; ++j) {
        float p = __expf(Ss[i][j] - m);
        Ss[i][j] = p;
        sum += p;
    }
    const float inv = 1.0f / sum;
    for (int j = 0; j < 64; ++j)
        Sca[((size_t)bh << 12) + i * 64 + j] = f2bf(Ss[i][j] * inv);
}

// ---------------------------------------------------------------------------
// Channel stage 3 via MFMA — unchanged from round 3.
// ---------------------------------------------------------------------------
__global__ __launch_bounds__(256) void chan_pv_mfma(const ushort* __restrict__ Sca,
                                                    const ushort* __restrict__ Pvc,
                                                    float* __restrict__ out)
{
    const int nc = blockIdx.x, hh = blockIdx.y, b = blockIdx.z;
    const int t = threadIdx.x;
    const int w = t >> 6, l = t & 63, c = l & 15, g = l >> 4;

    const ushort* S = Sca + ((size_t)(b * 4 + hh) << 12);
    const ushort* V = Pvc + (size_t)b * PROJ_EL + (size_t)hh * HEAD_EL;
    const int n0w = nc * 256 + w * 64;

    f32x4 acc[4][4] = {};
    #pragma unroll
    for (int ks = 0; ks < 2; ++ks) {
        short8_t af[4], bfr[4];
        #pragma unroll
        for (int rt = 0; rt < 4; ++rt)
            af[rt] = *(const short8_t*)&S[(size_t)(rt * 16 + c) * 64 + ks * 32 + 8 * g];
        #pragma unroll
        for (int ct = 0; ct < 4; ++ct)
            bfr[ct] = *(const short8_t*)&V[(size_t)(n0w + ct * 16 + c) * 64 + ks * 32 + 8 * g];
        #pragma unroll
        for (int rt = 0; rt < 4; ++rt)
            #pragma unroll
            for (int ct = 0; ct < 4; ++ct)
                acc[rt][ct] = __builtin_amdgcn_mfma_f32_16x16x32_bf16(
                    af[rt], bfr[ct], acc[rt][ct], 0, 0, 0);
    }

    float* ob = out + (size_t)b * (Nn * 320);
    #pragma unroll
    for (int rt = 0; rt < 4; ++rt)
        #pragma unroll
        for (int ct = 0; ct < 4; ++ct)
            #pragma unroll
            for (int r = 0; r < 4; ++r) {
                int i = rt * 16 + 4 * g + r;
                int nn = n0w + ct * 16 + c;
                int rem = hh * 131072 + i * 2048 + nn;
                ob[(rem >> 8) * 320 + (rem & 255)] = acc[rt][ct][r];
            }
}

// ---------------------------------------------------------------------------
// Spatial attention, round 10 = round 9 kernel with XCD-aware block decode.
// 1D grid of 1024 blocks; block i -> xcd = i&7 (round-robin dispatch), and we
// assign head hsel = xcd + 8*(j&1) so each XCD serves exactly 2 heads
// (K+V hot set 640 KB -> L2-resident). qb = j>>1 in [0,64). Work per block
// and all math bit-identical to r9's spatial_attn5.
// ---------------------------------------------------------------------------
#define LOADK9(dst, kbase)                                                       \
    {                                                                            \
        _Pragma("unroll")                                                        \
        for (int tc_ = 0; tc_ < 4; ++tc_) {                                      \
            const ushort* kp_ = Kh + (size_t)((kbase) + tc_ * 16 + c) * 64 + 8 * g; \
            dst[2 * tc_]     = *(const short8_t*)kp_;                            \
            dst[2 * tc_ + 1] = *(const short8_t*)(kp_ + 32);                     \
        }                                                                        \
    }
#define LOADV9(dst, kbase)                                                       \
    {                                                                            \
        _Pragma("unroll")                                                        \
        for (int ks_ = 0; ks_ < 2; ++ks_)                                        \
            dst[ks_] = *(const short8_t*)&Vt[(size_t)c * 2048 + (kbase) + ks_ * 32 + 8 * g]; \
    }
#define TILE9(kcur, vcur, knext, vnext, kbrow, doPref)                           \
    {                                                                            \
        f32x4 st9[4];                                                            \
        _Pragma("unroll")                                                        \
        for (int tc = 0; tc < 4; ++tc) {                                         \
            f32x4 z9 = {0.f, 0.f, 0.f, 0.f};                                     \
            z9 = __builtin_amdgcn_mfma_f32_16x16x32_bf16(kcur[2 * tc], qf0, z9, 0, 0, 0); \
            st9[tc] = __builtin_amdgcn_mfma_f32_16x16x32_bf16(kcur[2 * tc + 1], qf1, z9, 0, 0, 0); \
        }                                                                        \
        if (doPref) { LOADK9(knext, (kbrow) + 64); LOADV9(vnext, (kbrow) + 64); }\
        _Pragma("unroll")                                                        \
        for (int tc = 0; tc < 4; ++tc) {                                         \
            float p0 = __builtin_amdgcn_exp2f(st9[tc][0] * sT2);                 \
            float p1 = __builtin_amdgcn_exp2f(st9[tc][1] * sT2);                 \
            float p2 = __builtin_amdgcn_exp2f(st9[tc][2] * sT2);                 \
            float p3 = __builtin_amdgcn_exp2f(st9[tc][3] * sT2);                 \
            lsum += (p0 + p1) + (p2 + p3);                                       \
            unsigned u01, u23;                                                   \
            asm("v_cvt_pk_bf16_f32 %0, %1, %2" : "=v"(u01) : "v"(p0), "v"(p1));  \
            asm("v_cvt_pk_bf16_f32 %0, %1, %2" : "=v"(u23) : "v"(p2), "v"(p3));  \
            *(unsigned*)&Pw[(size_t)c * 72 + tc * 16 + 4 * g]     = u01;         \
            *(unsigned*)&Pw[(size_t)c * 72 + tc * 16 + 4 * g + 2] = u23;         \
        }                                                                        \
        __builtin_amdgcn_sched_barrier(0);                                       \
        _Pragma("unroll")                                                        \
        for (int ks = 0; ks < 2; ++ks) {                                         \
            short8_t pf9 = *(const short8_t*)&Pw[(size_t)c * 72 + ks * 32 + 8 * g]; \
            oacc = __builtin_amdgcn_mfma_f32_16x16x32_bf16(vcur[ks], pf9, oacc, 0, 0, 0); \
        }                                                                        \
    }

__global__ __launch_bounds__(512, 2) void spatial_attn6(
    const ushort* __restrict__ Pqs, const ushort* __restrict__ Pks,
    const ushort* __restrict__ PvsT, const float* __restrict__ temp2,
    float* __restrict__ out)
{
    // XCD-aware decode: block i -> xcd i&7; 2 heads per XCD; qb in [0,64)
    const int i0 = blockIdx.x;
    const int xcd = i0 & 7, j = i0 >> 3;
    const int hsel = xcd + 8 * (j & 1);      // 0..15 = b*4+hh
    const int qb = j >> 1;                   // 0..63
    const int b = hsel >> 2, hh = hsel & 3;

    const int t = threadIdx.x, w = t >> 6, l = t & 63;
    const int c = l & 15, g = l >> 4;
    const int qsub = w >> 2, kh = w & 3;    // wave = qsub*4 + kh

    __shared__ ushort P_lds[8][16][72];     // per-wave 16x64 P tile (pad 72)
    __shared__ float  O_red[8][16][16];     // [wave][q=c][d]
    __shared__ float  L_red[8][16];         // [wave][q=c]

    const ushort* Qh = Pqs + (size_t)b * PROJ_EL + (size_t)hh * HEAD_EL;
    const ushort* Kh = Pks + (size_t)b * PROJ_EL + (size_t)hh * HEAD_EL;
    const ushort* Vt = PvsT + (size_t)((b * 4 + hh) * 16) * 2048;   // (16, 2048)
    const float sT2 = 0.125f * temp2[hh] * 1.44269504f;   // fold log2(e)

    const int q0 = qb * 32 + qsub * 16;
    const ushort* qp = Qh + (size_t)(q0 + c) * 64 + 8 * g;
    const short8_t qf0 = *(const short8_t*)qp;
    const short8_t qf1 = *(const short8_t*)(qp + 32);

    f32x4 oacc = {0.f, 0.f, 0.f, 0.f};
    float lsum = 0.f;
    ushort* Pw = &P_lds[w][0][0];           // row stride 72 ushorts

    short8_t kA[8], kB[8], vA[2], vB[2];
    const int kb0 = kh * 8 * 64;            // row base of this wave's quarter
    LOADK9(kA, kb0);
    LOADV9(vA, kb0);

    #pragma unroll
    for (int ii = 0; ii < 4; ++ii) {
        const int kb = (kh * 8 + 2 * ii) * 64;
        TILE9(kA, vA, kB, vB, kb, 1);                 // tile 2*ii   (prefetch 2*ii+1)
        TILE9(kB, vB, kA, vA, kb + 64, (ii < 3));     // tile 2*ii+1 (prefetch 2*ii+2)
    }

    // per-wave full row-sum for q = c (across the 4 lane-groups)
    lsum += __shfl_xor(lsum, 16);
    lsum += __shfl_xor(lsum, 32);

    // stash partials and combine the 4 KV-quarters
    *(float4*)&O_red[w][c][4 * g] = make_float4(oacc[0], oacc[1], oacc[2], oacc[3]);
    if (g == 0) L_red[w][c] = lsum;
    __syncthreads();

    if (kh == 0) {
        float4 osum = make_float4(0.f, 0.f, 0.f, 0.f);
        float ltot = 0.f;
        #pragma unroll
        for (int k2 = 0; k2 < 4; ++k2) {
            float4 ov = *(const float4*)&O_red[qsub * 4 + k2][c][4 * g];
            osum.x += ov.x; osum.y += ov.y; osum.z += ov.z; osum.w += ov.w;
            ltot += L_red[qsub * 4 + k2][c];
        }
        const float inv = 1.0f / ltot;
        // raw-reshape scatter: nn = q-row; row n, cols 256+(nn&3)*16+4g..+3
        const int nn = q0 + c;
        const int n = hh * 512 + (nn >> 2);
        const int cc = 256 + ((nn & 3) << 4) + 4 * g;
        float4 o4 = make_float4(osum.x * inv, osum.y * inv, osum.z * inv, osum.w * inv);
        *(float4*)&out[((size_t)b * Nn + n) * 320 + cc] = o4;
    }
}

// ---------------------------------------------------------------------------
extern "C" void kernel_launch(void* const* d_in, const int* in_sizes, int n_in,
                              void* d_out, int out_size, void* d_ws, size_t ws_size,
                              hipStream_t stream)
{
    const float* s     = (const float*)d_in[0];
    const float* h     = (const float*)d_in[1];
    const float* sh    = (const float*)d_in[2];
    const float* temp  = (const float*)d_in[3];
    const float* temp2 = (const float*)d_in[4];
    const float* Wq_c  = (const float*)d_in[5];
    const float* Wq_s  = (const float*)d_in[6];
    const float* Wk_c  = (const float*)d_in[7];
    const float* Wv_c  = (const float*)d_in[8];
    const float* Wk_s  = (const float*)d_in[9];
    const float* Wv_s  = (const float*)d_in[10];
    float* out = (float*)d_out;
    float* ws = (float*)d_ws;

    ushort* sb    = (ushort*)(ws + OFF_SB);
    ushort* shb   = (ushort*)(ws + OFF_SHB);
    ushort* hb    = (ushort*)(ws + OFF_HB);
    ushort* wqcb  = (ushort*)(ws + OFF_WQC);
    ushort* wcatb = (ushort*)(ws + OFF_WCAT);
    ushort* wvsb  = (ushort*)(ws + OFF_WVS);
    ushort* Pqc   = (ushort*)(ws + OFF_PQC);
    ushort* Pqs   = (ushort*)(ws + OFF_PQS);
    ushort* Pkc   = (ushort*)(ws + OFF_PKC);
    ushort* Pvc   = (ushort*)(ws + OFF_PVC);
    ushort* Pks   = (ushort*)(ws + OFF_PKS);
    ushort* PvsT  = (ushort*)(ws + OFF_PVST);
    float*  part  = ws + OFF_PART;
    ushort* Sca   = (ushort*)(ws + OFF_SCA);

    const dim3 blk(256);

    // 1) f32 -> bf16 conversions
    convert_all<<<dim3((SEG8 / 8 + 255) / 256), blk, 0, stream>>>(
        s, sh, h, Wq_c, Wq_s, Wk_c, Wv_c, Wk_s, Wv_s,
        sb, shb, hb, wqcb, wcatb, wvsb);

    // 2) projections
    mfma_gemm<<<dim3(8, 64), blk, 0, stream>>>(shb, wcatb, Pqs, Pkc, Pvc, Pks, 256);
    mfma_gemm<<<dim3(2, 64), blk, 0, stream>>>(sb, wqcb, Pqc, Pqc, Pqc, Pqc, 256);
    mfma_gemm_vs<<<dim3(32), blk, 0, stream>>>(wvsb, hb, PvsT);

    // 3) channel branch
    chan_qk_partial<<<dim3(8, 4, 4), blk, 0, stream>>>(Pqc, Pkc, part);
    chan_softmax<<<dim3(16), dim3(64), 0, stream>>>(part, temp, Sca);
    chan_pv_mfma<<<dim3(8, 4, 4), blk, 0, stream>>>(Sca, Pvc, out);

    // 4) spatial branch (r9 + XCD-aware block swizzle, 1D grid)
    spatial_attn6<<<dim3(1024), dim3(512), 0, stream>>>(Pqs, Pks, PvsT, temp2, out);
}

// Round 11
// 87.608 us; speedup vs baseline: 1.5423x; 1.5423x over previous
//
#include <hip/hip_runtime.h>
#include <math.h>

// ---------------------------------------------------------------------------
// WCSA round 11: spatial kernel = r6's lane-local-softmax math (verified) +
// r2's block-level LDS staging path (verified). Diagnosis r10: per-tile
// global fragment loads were serialized (~2.9K cyc/tile, VGPR-starved);
// fix = stage K/V tiles once per block into double-buffered LDS (reg-staged,
// issued one tile early), fragments via ds_read_b128. XCD decode kept (r10).
// Projections/channel branch unchanged from round 3 (verified).
// ---------------------------------------------------------------------------

constexpr int Bb = 4, Nn = 2048, Hh = 4;
constexpr int PROJ_EL = Nn * 256;          // elements per batch, 256-col proj
constexpr int HEAD_EL = Nn * 64;           // elements per (b,h) head, d=64

typedef __attribute__((ext_vector_type(8))) short short8_t;   // 8 bf16
typedef __attribute__((ext_vector_type(4))) float f32x4;

__device__ __forceinline__ ushort f2bf(float x) {
    union { float f; unsigned u; } v; v.f = x;
    unsigned r = v.u + 0x7fffu + ((v.u >> 16) & 1u);   // RNE
    return (ushort)(r >> 16);
}
__device__ __forceinline__ float bf2f(ushort x) {
    union { unsigned u; float f; } v; v.u = ((unsigned)x) << 16;
    return v.f;
}

// ---------------- workspace layout (float granularity) ---------------------
constexpr size_t OFF_SB    = 0;                                   // s bf16
constexpr size_t OFF_SHB   = OFF_SB   + 1024 * 1024;              // sh bf16
constexpr size_t OFF_HB    = OFF_SHB  + 1024 * 1024;              // h bf16
constexpr size_t OFF_WQC   = OFF_HB   + 256 * 1024;               // Wq_c bf16
constexpr size_t OFF_WCAT  = OFF_WQC  + 32 * 1024;                // 4x64K el
constexpr size_t OFF_PQC   = OFF_WCAT + 128 * 1024;               // bf16 (8192,256)
constexpr size_t OFF_PQS   = OFF_PQC  + 1024 * 1024;
constexpr size_t OFF_PKC   = OFF_PQS  + 1024 * 1024;
constexpr size_t OFF_PVC   = OFF_PKC  + 1024 * 1024;
constexpr size_t OFF_PKS   = OFF_PVC  + 1024 * 1024;
constexpr size_t OFF_PVST  = OFF_PKS  + 1024 * 1024;              // bf16 (B,H,16,2048)
constexpr size_t OFF_PART  = OFF_PVST + 256 * 1024;               // f32 16*8*4096
constexpr size_t OFF_SCA   = OFF_PART + 512 * 1024;               // bf16 16*4096
constexpr size_t OFF_WVS   = OFF_SCA  + 32 * 1024;                // Wv_s bf16 (64,64)

// ---------------------------------------------------------------------------
// Convert all needed f32 arrays to bf16 in one pass. 8 elements per thread.
// ---------------------------------------------------------------------------
constexpr unsigned SEG0 = 2097152;              // s
constexpr unsigned SEG1 = SEG0 + 2097152;       // sh
constexpr unsigned SEG2 = SEG1 + 524288;        // h
constexpr unsigned SEG3 = SEG2 + 65536;         // Wq_c
constexpr unsigned SEG4 = SEG3 + 65536;         // Wq_s  -> Wcat+0
constexpr unsigned SEG5 = SEG4 + 65536;         // Wk_c  -> Wcat+65536
constexpr unsigned SEG6 = SEG5 + 65536;         // Wv_c  -> Wcat+131072
constexpr unsigned SEG7 = SEG6 + 65536;         // Wk_s  -> Wcat+196608
constexpr unsigned SEG8 = SEG7 + 4096;          // Wv_s

__global__ __launch_bounds__(256) void convert_all(
    const float* __restrict__ s, const float* __restrict__ sh,
    const float* __restrict__ h, const float* __restrict__ wqc,
    const float* __restrict__ wqs, const float* __restrict__ wkc,
    const float* __restrict__ wvc, const float* __restrict__ wks,
    const float* __restrict__ wvs,
    ushort* __restrict__ sb, ushort* __restrict__ shb, ushort* __restrict__ hb,
    ushort* __restrict__ wqcb, ushort* __restrict__ wcatb, ushort* __restrict__ wvsb)
{
    unsigned e = (blockIdx.x * 256u + threadIdx.x) * 8u;
    if (e >= SEG8) return;
    const float* src; ushort* dst; unsigned off;
    if      (e < SEG0) { src = s;   dst = sb;             off = e; }
    else if (e < SEG1) { src = sh;  dst = shb;            off = e - SEG0; }
    else if (e < SEG2) { src = h;   dst = hb;             off = e - SEG1; }
    else if (e < SEG3) { src = wqc; dst = wqcb;           off = e - SEG2; }
    else if (e < SEG4) { src = wqs; dst = wcatb;          off = e - SEG3; }
    else if (e < SEG5) { src = wkc; dst = wcatb + 65536;  off = e - SEG4; }
    else if (e < SEG6) { src = wvc; dst = wcatb + 131072; off = e - SEG5; }
    else if (e < SEG7) { src = wks; dst = wcatb + 196608; off = e - SEG6; }
    else               { src = wvs; dst = wvsb;           off = e - SEG7; }
    float4 f0 = *(const float4*)&src[off];
    float4 f1 = *(const float4*)&src[off + 4];
    short8_t o;
    o[0] = f2bf(f0.x); o[1] = f2bf(f0.y); o[2] = f2bf(f0.z); o[3] = f2bf(f0.w);
    o[4] = f2bf(f1.x); o[5] = f2bf(f1.y); o[6] = f2bf(f1.z); o[7] = f2bf(f1.w);
    *(short8_t*)&dst[off] = o;
}

// ---------------------------------------------------------------------------
// bf16 MFMA GEMM: C = X(M,K) @ W(Ntot,K)^T, bf16 out, routed to one of four
// 256-col destination buffers by global column segment. 128x128 tile, BK=64.
// (unchanged from round 3, verified)
// ---------------------------------------------------------------------------
__global__ __launch_bounds__(256) void mfma_gemm(
    const ushort* __restrict__ X, const ushort* __restrict__ W,
    ushort* __restrict__ d0, ushort* __restrict__ d1,
    ushort* __restrict__ d2, ushort* __restrict__ d3, int K)
{
    __shared__ ushort Xs[128][72];
    __shared__ ushort Ws[128][72];
    const int t = threadIdx.x;
    const int w = t >> 6, l = t & 63, c = l & 15, g = l >> 4;
    const int wr = w >> 1, wc = w & 1;
    const int m0 = blockIdx.y * 128, n0 = blockIdx.x * 128;

    f32x4 acc[4][4] = {};

    const int srow = t >> 2, scs = (t & 3) * 16;
    for (int k0 = 0; k0 < K; k0 += 64) {
        __syncthreads();
        #pragma unroll
        for (int p = 0; p < 2; ++p) {
            const ushort* xs = &X[(size_t)(m0 + p * 64 + srow) * K + k0 + scs];
            *(short8_t*)&Xs[p * 64 + srow][scs]     = *(const short8_t*)xs;
            *(short8_t*)&Xs[p * 64 + srow][scs + 8] = *(const short8_t*)(xs + 8);
            const ushort* wsp = &W[(size_t)(n0 + p * 64 + srow) * K + k0 + scs];
            *(short8_t*)&Ws[p * 64 + srow][scs]     = *(const short8_t*)wsp;
            *(short8_t*)&Ws[p * 64 + srow][scs + 8] = *(const short8_t*)(wsp + 8);
        }
        __syncthreads();
        #pragma unroll
        for (int ks = 0; ks < 2; ++ks) {
            short8_t af[4], bf[4];
            #pragma unroll
            for (int rt = 0; rt < 4; ++rt)
                af[rt] = *(const short8_t*)&Xs[wr * 64 + rt * 16 + c][ks * 32 + 8 * g];
            #pragma unroll
            for (int ct = 0; ct < 4; ++ct)
                bf[ct] = *(const short8_t*)&Ws[wc * 64 + ct * 16 + c][ks * 32 + 8 * g];
            #pragma unroll
            for (int rt = 0; rt < 4; ++rt)
                #pragma unroll
                for (int ct = 0; ct < 4; ++ct)
                    acc[rt][ct] = __builtin_amdgcn_mfma_f32_16x16x32_bf16(
                        af[rt], bf[ct], acc[rt][ct], 0, 0, 0);
        }
    }

    const int seg = n0 >> 8;
    ushort* dst = seg == 0 ? d0 : seg == 1 ? d1 : seg == 2 ? d2 : d3;
    const int colbase = (n0 & 255) + wc * 64;
    #pragma unroll
    for (int rt = 0; rt < 4; ++rt)
        #pragma unroll
        for (int ct = 0; ct < 4; ++ct)
            #pragma unroll
            for (int r = 0; r < 4; ++r) {
                int mrow = m0 + wr * 64 + rt * 16 + 4 * g + r;
                int col = colbase + ct * 16 + c;
                dst[(size_t)mrow * 256 + col] = f2bf(acc[rt][ct][r]);
            }
}

// ---------------------------------------------------------------------------
// v_s^T producer with raw-reshape-aware scatter (verified round 6).
// ---------------------------------------------------------------------------
__global__ __launch_bounds__(256) void mfma_gemm_vs(
    const ushort* __restrict__ Wvs, const ushort* __restrict__ Hb,
    ushort* __restrict__ Cvt)
{
    const int t = threadIdx.x;
    const int w = t >> 6, l = t & 63, c = l & 15, g = l >> 4;
    const int n0 = blockIdx.x * 256 + w * 64;

    f32x4 acc[4][4] = {};
    #pragma unroll
    for (int ks = 0; ks < 2; ++ks) {
        short8_t af[4], bfr[4];
        #pragma unroll
        for (int rt = 0; rt < 4; ++rt)
            af[rt] = *(const short8_t*)&Wvs[(size_t)(rt * 16 + c) * 64 + ks * 32 + 8 * g];
        #pragma unroll
        for (int ct = 0; ct < 4; ++ct)
            bfr[ct] = *(const short8_t*)&Hb[(size_t)(n0 + ct * 16 + c) * 64 + ks * 32 + 8 * g];
        #pragma unroll
        for (int rt = 0; rt < 4; ++rt)
            #pragma unroll
            for (int ct = 0; ct < 4; ++ct)
                acc[rt][ct] = __builtin_amdgcn_mfma_f32_16x16x32_bf16(
                    af[rt], bfr[ct], acc[rt][ct], 0, 0, 0);
    }
    #pragma unroll
    for (int rt = 0; rt < 4; ++rt)
        #pragma unroll
        for (int ct = 0; ct < 4; ++ct)
            #pragma unroll
            for (int r = 0; r < 4; ++r) {
                int cc = rt * 16 + 4 * g + r;       // output channel 0..63
                int m  = n0 + ct * 16 + c;          // global row 0..8191
                int b  = m >> 11, n = m & 2047;
                int L  = n * 64 + cc;               // within-batch flat index
                int hh = L >> 15;
                int k  = (L & 32767) >> 4;
                int d  = L & 15;
                Cvt[(size_t)((b * 4 + hh) * 16 + d) * 2048 + k] = f2bf(acc[rt][ct][r]);
            }
}

// ---------------------------------------------------------------------------
// Channel stage 1 (f32 compute, bf16 input) — unchanged from round 3.
// ---------------------------------------------------------------------------
__global__ __launch_bounds__(256) void chan_qk_partial(const ushort* __restrict__ Pqc,
                                                       const ushort* __restrict__ Pkc,
                                                       float* __restrict__ part)
{
    const int ch = blockIdx.x, hh = blockIdx.y, b = blockIdx.z;
    const ushort* Q = Pqc + (size_t)b * PROJ_EL + (size_t)hh * HEAD_EL;
    const ushort* Kk = Pkc + (size_t)b * PROJ_EL + (size_t)hh * HEAD_EL;
    __shared__ float Qs[64][68], Ks[64][68];
    const int t = threadIdx.x, ty = t >> 4, tx = t & 15;

    float acc[4][4] = {};
    for (int sub = 0; sub < 4; ++sub) {
        const int r0 = ch * 256 + sub * 64;
        __syncthreads();
        #pragma unroll
        for (int q = t; q < 512; q += 256) {
            int row = q >> 3, c8 = (q & 7) * 8;
            short8_t qv = *(const short8_t*)&Q[(size_t)(r0 + row) * 64 + c8];
            short8_t kv = *(const short8_t*)&Kk[(size_t)(r0 + row) * 64 + c8];
            #pragma unroll
            for (int j = 0; j < 8; ++j) {
                Qs[row][c8 + j] = bf2f((ushort)qv[j]);
                Ks[row][c8 + j] = bf2f((ushort)kv[j]);
            }
        }
        __syncthreads();
        #pragma unroll 8
        for (int nn = 0; nn < 64; ++nn) {
            float4 q4 = *(const float4*)&Qs[nn][ty * 4];
            float4 k4 = *(const float4*)&Ks[nn][tx * 4];
            float qa[4] = {q4.x, q4.y, q4.z, q4.w};
            float ka[4] = {k4.x, k4.y, k4.z, k4.w};
            #pragma unroll
            for (int ii = 0; ii < 4; ++ii)
                #pragma unroll
                for (int jj = 0; jj < 4; ++jj)
                    acc[ii][jj] += qa[ii] * ka[jj];
        }
    }
    float* P = part + (((size_t)(b * 4 + hh) * 8 + ch) << 12);
    #pragma unroll
    for (int ii = 0; ii < 4; ++ii)
        *(float4*)&P[(ty * 4 + ii) * 64 + tx * 4] =
            make_float4(acc[ii][0], acc[ii][1], acc[ii][2], acc[ii][3]);
}

// ---------------------------------------------------------------------------
// Channel stage 2 — unchanged from round 3.
// ---------------------------------------------------------------------------
__global__ __launch_bounds__(64) void chan_softmax(const float* __restrict__ part,
                                                   const float* __restrict__ temp,
                                                   ushort* __restrict__ Sca)
{
    const int bh = blockIdx.x;
    const int hsel = bh & 3;
    const int i = threadIdx.x;
    __shared__ float Ss[64][65];
    const float sT = 0.125f * temp[hsel];

    float m = -1e30f;
    for (int j = 0; j < 64; ++j) {
        float v = 0.f;
        #pragma unroll
        for (int cc = 0; cc < 8; ++cc)
            v += part[((size_t)bh * 8 + cc) * 4096 + i * 64 + j];
        v *= sT;
        Ss[i][j] = v;
        m = fmaxf(m, v);
    }
    float sum = 0.f;
    for (int j = 0; j < 64; ++j) {
        float p = __expf(Ss[i][j] - m);
        Ss[i][j] = p;
        sum += p;
    }
    const float inv = 1.0f / sum;
    for (int j = 0; j < 64; ++j)
        Sca[((size_t)bh << 12) + i * 64 + j] = f2bf(Ss[i][j] * inv);
}

// ---------------------------------------------------------------------------
// Channel stage 3 via MFMA — unchanged from round 3.
// ---------------------------------------------------------------------------
__global__ __launch_bounds__(256) void chan_pv_mfma(const ushort* __restrict__ Sca,
                                                    const ushort* __restrict__ Pvc,
                                                    float* __restrict__ out)
{
    const int nc = blockIdx.x, hh = blockIdx.y, b = blockIdx.z;
    const int t = threadIdx.x;
    const int w = t >> 6, l = t & 63, c = l & 15, g = l >> 4;

    const ushort* S = Sca + ((size_t)(b * 4 + hh) << 12);
    const ushort* V = Pvc + (size_t)b * PROJ_EL + (size_t)hh * HEAD_EL;
    const int n0w = nc * 256 + w * 64;

    f32x4 acc[4][4] = {};
    #pragma unroll
    for (int ks = 0; ks < 2; ++ks) {
        short8_t af[4], bfr[4];
        #pragma unroll
        for (int rt = 0; rt < 4; ++rt)
            af[rt] = *(const short8_t*)&S[(size_t)(rt * 16 + c) * 64 + ks * 32 + 8 * g];
        #pragma unroll
        for (int ct = 0; ct < 4; ++ct)
            bfr[ct] = *(const short8_t*)&V[(size_t)(n0w + ct * 16 + c) * 64 + ks * 32 + 8 * g];
        #pragma unroll
        for (int rt = 0; rt < 4; ++rt)
            #pragma unroll
            for (int ct = 0; ct < 4; ++ct)
                acc[rt][ct] = __builtin_amdgcn_mfma_f32_16x16x32_bf16(
                    af[rt], bfr[ct], acc[rt][ct], 0, 0, 0);
    }

    float* ob = out + (size_t)b * (Nn * 320);
    #pragma unroll
    for (int rt = 0; rt < 4; ++rt)
        #pragma unroll
        for (int ct = 0; ct < 4; ++ct)
            #pragma unroll
            for (int r = 0; r < 4; ++r) {
                int i = rt * 16 + 4 * g + r;
                int nn = n0w + ct * 16 + c;
                int rem = hh * 131072 + i * 2048 + nn;
                ob[(rem >> 8) * 320 + (rem & 255)] = acc[rt][ct][r];
            }
}

// ---------------------------------------------------------------------------
// Spatial attention, round 11. 256 blocks (XCD-decoded: 2 heads per XCD) x
// 512 thr = 8 waves; block owns 128 q-rows (16 per wave), loops 32 KV tiles.
// Per tile: block stages K (64x64 bf16) + V^T (16x64) into double-buffered
// padded LDS (reg-staged, loads issued one tile early); each wave reads MFMA
// fragments via ds_read_b128 (r2-verified layout). Softmax lane-local via
// swapped QK^T (r6-verified), no max-subtraction. Epilogue = r6's (verified).
// ---------------------------------------------------------------------------
__global__ __launch_bounds__(512, 2) void spatial_attn7(
    const ushort* __restrict__ Pqs, const ushort* __restrict__ Pks,
    const ushort* __restrict__ PvsT, const float* __restrict__ temp2,
    float* __restrict__ out)
{
    // XCD-aware decode: 256 blocks; xcd = i&7 serves heads xcd and xcd+8
    const int i0 = blockIdx.x;
    const int xcd = i0 & 7, j = i0 >> 3;       // j in [0,32)
    const int hsel = xcd + 8 * (j & 1);        // 0..15 = b*4+hh
    const int qb = j >> 1;                     // 0..15
    const int b = hsel >> 2, hh = hsel & 3;

    const int t = threadIdx.x, w = t >> 6, l = t & 63;
    const int c = l & 15, g = l >> 4;

    __shared__ ushort Kbuf[2][64][72];         // 18.4 KB
    __shared__ ushort Vbuf[2][16][72];         //  4.6 KB
    __shared__ ushort P_lds[8][16][72];        // 18.4 KB (per-wave P tile)

    const ushort* Qh = Pqs + (size_t)b * PROJ_EL + (size_t)hh * HEAD_EL;
    const ushort* Kh = Pks + (size_t)b * PROJ_EL + (size_t)hh * HEAD_EL;
    const ushort* Vt = PvsT + (size_t)((b * 4 + hh) * 16) * 2048;   // (16, 2048)
    const float sT2 = 0.125f * temp2[hh] * 1.44269504f;   // fold log2(e)

    const int q0 = qb * 128 + w * 16;
    const ushort* qp = Qh + (size_t)(q0 + c) * 64 + 8 * g;
    const short8_t qf0 = *(const short8_t*)qp;
    const short8_t qf1 = *(const short8_t*)(qp + 32);

    f32x4 oacc = {0.f, 0.f, 0.f, 0.f};
    float lsum = 0.f;
    ushort* Pw = &P_lds[w][0][0];              // row stride 72 ushorts

    // staging geometry: K 8KB -> 512 thr x 16B; V 2KB -> 512 thr x 4B
    const int krow = t >> 3, ksub = (t & 7) * 8;
    const int vrow = t >> 5, vcol = (t & 31) * 2;

    // prologue: stage tile 0 into buffer 0
    short8_t kreg = *(const short8_t*)&Kh[(size_t)krow * 64 + ksub];
    uint vreg = *(const uint*)&Vt[(size_t)vrow * 2048 + vcol];
    *(short8_t*)&Kbuf[0][krow][ksub] = kreg;
    *(uint*)&Vbuf[0][vrow][vcol] = vreg;

    for (int kt = 0; kt < 32; ++kt) {
        const int kb = kt * 64;
        const int cur = kt & 1;

        // issue next tile's global loads now; latency hides under compute
        if (kt < 31) {
            kreg = *(const short8_t*)&Kh[(size_t)(kb + 64 + krow) * 64 + ksub];
            vreg = *(const uint*)&Vt[(size_t)vrow * 2048 + kb + 64 + vcol];
        }

        __syncthreads();   // staging of tile kt visible to all waves

        // S^T row-tiles: A = K rows (LDS), B = Q regs; then lane-local softmax
        #pragma unroll
        for (int tc = 0; tc < 4; ++tc) {
            short8_t kf0 = *(const short8_t*)&Kbuf[cur][tc * 16 + c][8 * g];
            short8_t kf1 = *(const short8_t*)&Kbuf[cur][tc * 16 + c][32 + 8 * g];
            f32x4 st = {0.f, 0.f, 0.f, 0.f};
            st = __builtin_amdgcn_mfma_f32_16x16x32_bf16(kf0, qf0, st, 0, 0, 0);
            st = __builtin_amdgcn_mfma_f32_16x16x32_bf16(kf1, qf1, st, 0, 0, 0);
            float p0 = __builtin_amdgcn_exp2f(st[0] * sT2);
            float p1 = __builtin_amdgcn_exp2f(st[1] * sT2);
            float p2 = __builtin_amdgcn_exp2f(st[2] * sT2);
            float p3 = __builtin_amdgcn_exp2f(st[3] * sT2);
            lsum += (p0 + p1) + (p2 + p3);
            unsigned u01, u23;
            asm("v_cvt_pk_bf16_f32 %0, %1, %2" : "=v"(u01) : "v"(p0), "v"(p1));
            asm("v_cvt_pk_bf16_f32 %0, %1, %2" : "=v"(u23) : "v"(p2), "v"(p3));
            *(unsigned*)&Pw[(size_t)c * 72 + tc * 16 + 4 * g]     = u01;
            *(unsigned*)&Pw[(size_t)c * 72 + tc * 16 + 4 * g + 2] = u23;
        }
        __builtin_amdgcn_sched_barrier(0);
        // O^T += V^T * P^T (V from LDS, P per-wave LDS)
        #pragma unroll
        for (int ks = 0; ks < 2; ++ks) {
            short8_t vf = *(const short8_t*)&Vbuf[cur][c][ks * 32 + 8 * g];
            short8_t pf = *(const short8_t*)&Pw[(size_t)c * 72 + ks * 32 + 8 * g];
            oacc = __builtin_amdgcn_mfma_f32_16x16x32_bf16(vf, pf, oacc, 0, 0, 0);
        }

        __syncthreads();   // all waves done reading buf[cur]

        if (kt < 31) {     // write next tile into the other buffer
            *(short8_t*)&Kbuf[cur ^ 1][krow][ksub] = kreg;
            *(uint*)&Vbuf[cur ^ 1][vrow][vcol] = vreg;
        }
    }

    // full row-sum for q = c: reduce across the 4 lane-groups holding it
    lsum += __shfl_xor(lsum, 16);
    lsum += __shfl_xor(lsum, 32);
    const float inv = 1.0f / lsum;

    // raw-reshape scatter: nn = q-row; row n, cols 256+(nn&3)*16+4g..+3
    const int nn = q0 + c;
    const int n = hh * 512 + (nn >> 2);
    const int cc = 256 + ((nn & 3) << 4) + 4 * g;
    float4 o4 = make_float4(oacc[0] * inv, oacc[1] * inv, oacc[2] * inv, oacc[3] * inv);
    *(float4*)&out[((size_t)b * Nn + n) * 320 + cc] = o4;
}

// ---------------------------------------------------------------------------
extern "C" void kernel_launch(void* const* d_in, const int* in_sizes, int n_in,
                              void* d_out, int out_size, void* d_ws, size_t ws_size,
                              hipStream_t stream)
{
    const float* s     = (const float*)d_in[0];
    const float* h     = (const float*)d_in[1];
    const float* sh    = (const float*)d_in[2];
    const float* temp  = (const float*)d_in[3];
    const float* temp2 = (const float*)d_in[4];
    const float* Wq_c  = (const float*)d_in[5];
    const float* Wq_s  = (const float*)d_in[6];
    const float* Wk_c  = (const float*)d_in[7];
    const float* Wv_c  = (const float*)d_in[8];
    const float* Wk_s  = (const float*)d_in[9];
    const float* Wv_s  = (const float*)d_in[10];
    float* out = (float*)d_out;
    float* ws = (float*)d_ws;

    ushort* sb    = (ushort*)(ws + OFF_SB);
    ushort* shb   = (ushort*)(ws + OFF_SHB);
    ushort* hb    = (ushort*)(ws + OFF_HB);
    ushort* wqcb  = (ushort*)(ws + OFF_WQC);
    ushort* wcatb = (ushort*)(ws + OFF_WCAT);
    ushort* wvsb  = (ushort*)(ws + OFF_WVS);
    ushort* Pqc   = (ushort*)(ws + OFF_PQC);
    ushort* Pqs   = (ushort*)(ws + OFF_PQS);
    ushort* Pkc   = (ushort*)(ws + OFF_PKC);
    ushort* Pvc   = (ushort*)(ws + OFF_PVC);
    ushort* Pks   = (ushort*)(ws + OFF_PKS);
    ushort* PvsT  = (ushort*)(ws + OFF_PVST);
    float*  part  = ws + OFF_PART;
    ushort* Sca   = (ushort*)(ws + OFF_SCA);

    const dim3 blk(256);

    // 1) f32 -> bf16 conversions
    convert_all<<<dim3((SEG8 / 8 + 255) / 256), blk, 0, stream>>>(
        s, sh, h, Wq_c, Wq_s, Wk_c, Wv_c, Wk_s, Wv_s,
        sb, shb, hb, wqcb, wcatb, wvsb);

    // 2) projections
    mfma_gemm<<<dim3(8, 64), blk, 0, stream>>>(shb, wcatb, Pqs, Pkc, Pvc, Pks, 256);
    mfma_gemm<<<dim3(2, 64), blk, 0, stream>>>(sb, wqcb, Pqc, Pqc, Pqc, Pqc, 256);
    mfma_gemm_vs<<<dim3(32), blk, 0, stream>>>(wvsb, hb, PvsT);

    // 3) channel branch
    chan_qk_partial<<<dim3(8, 4, 4), blk, 0, stream>>>(Pqc, Pkc, part);
    chan_softmax<<<dim3(16), dim3(64), 0, stream>>>(part, temp, Sca);
    chan_pv_mfma<<<dim3(8, 4, 4), blk, 0, stream>>>(Sca, Pvc, out);

    // 4) spatial branch (LDS-staged K/V double-buffer + lane-local softmax)
    spatial_attn7<<<dim3(256), dim3(512), 0, stream>>>(Pqs, Pks, PvsT, temp2, out);
}